// Round 12
// baseline (101.201 us; speedup 1.0000x reference)
//
#include <hip/hip_runtime.h>

// CrossProductLayer: out[b, f] = t(b, f) * w[f]
//   f in [0,128)    : x[b,f]^2
//   f in [128,256)  : x[b,f-128]
//   f in [256,8384) : x[b,i]*x[b,j]*0.5, (i,j) = triu_indices(128, k=1)[f-256]
// B=16384, F=8384. 549 MB fp32 output -> HBM-write-bound.
//
// R12 = R11 (96.7 us) with BROWS 128: block count halves again (4224),
// halving per-block setup/barrier events; decode amortized 128x. 64 KB LDS
// -> 2 blocks/CU = 8 waves/CU, still above the ~3.5 waves/CU where the
// 6.65 TB/s fill kernel saturates. nt dword stores; decode + w-load hoisted
// above staging (R11); lane-stride-1 LDS reads (conflict-free since R2).
// fp-exact: same op order as R2/R10/R11 (absmax 0.0 in R2-R11).

constexpr int BATCH = 16384;
constexpr int NIN   = 128;
constexpr int NFEAT = 2 * NIN + NIN * (NIN - 1) / 2;  // 8384
constexpr int TPB   = 256;
constexpr int BROWS = 128;

__device__ __forceinline__ int pair_off(int i) { return i * (NIN - 1) - (i * (i - 1)) / 2; }

__global__ __launch_bounds__(TPB) void cpl_kernel(const float* __restrict__ x,
                                                  const float* __restrict__ w,
                                                  float* __restrict__ out) {
    __shared__ float xs[BROWS * NIN];  // 64 KB

    const int tid = threadIdx.x;
    const int b0  = blockIdx.y * BROWS;
    const int f   = blockIdx.x * TPB + tid;
    const int fc  = min(f, NFEAT - 1);  // clamp for safe early decode/load

    // Issue w-load + decode FIRST: latency overlaps the staging loads below.
    const float wf = w[fc];
    int i1, i2, mode;  // 0=square, 1=single, 2=pair
    if (fc < NIN) {
        i1 = fc; i2 = fc; mode = 0;
    } else if (fc < 2 * NIN) {
        i1 = fc - NIN; i2 = fc - NIN; mode = 1;
    } else {
        const int p = fc - 2 * NIN;
        float s = sqrtf((float)(65025 - 8 * p));  // invert off(i) <= p
        int   i = (int)((255.0f - s) * 0.5f);
        i = min(max(i, 0), NIN - 2);
        while (pair_off(i + 1) <= p) ++i;  // exact integer fix-up
        while (pair_off(i)     >  p) --i;
        i1 = i;
        i2 = i + 1 + (p - pair_off(i));
        mode = 2;
    }

    // Cooperative tile load: 128 rows x 128 floats = 4096 float4, 16/thread.
    {
        const float4* src = reinterpret_cast<const float4*>(x + (size_t)b0 * NIN);
        float4*       dst = reinterpret_cast<float4*>(xs);
#pragma unroll
        for (int k = 0; k < (BROWS * NIN / 4) / TPB; ++k)
            dst[k * TPB + tid] = src[k * TPB + tid];
    }
    __syncthreads();

    if (f >= NFEAT) return;

    float* op = out + (size_t)b0 * NFEAT + f;
#pragma unroll
    for (int b = 0; b < BROWS; ++b) {
        const float xi = xs[b * NIN + i1];
        const float xj = xs[b * NIN + i2];  // lane-stride-1: conflict-free
        float p = xi * xj;                  // squares & pairs
        if (mode == 1) p = xi;              // singles
        if (mode == 2) p *= 0.5f;           // pairs (same fp order as ref)
        __builtin_nontemporal_store(p * wf, op + (size_t)b * NFEAT);
    }
}

extern "C" void kernel_launch(void* const* d_in, const int* in_sizes, int n_in,
                              void* d_out, int out_size, void* d_ws, size_t ws_size,
                              hipStream_t stream) {
    const float* x = (const float*)d_in[0];  // [16384, 128]
    const float* w = (const float*)d_in[1];  // [8384]
    float*     out = (float*)d_out;          // [16384, 8384]

    dim3 grid((NFEAT + TPB - 1) / TPB,  // 33 feature windows
              BATCH / BROWS);           // 128 row groups
    cpl_kernel<<<grid, TPB, 0, stream>>>(x, w, out);
}

// Round 13
// 96.813 us; speedup vs baseline: 1.0453x; 1.0453x over previous
//
#include <hip/hip_runtime.h>

// CrossProductLayer: out[b, f] = t(b, f) * w[f]
//   f in [0,128)    : x[b,f]^2
//   f in [128,256)  : x[b,f-128]
//   f in [256,8384) : x[b,i]*x[b,j]*0.5, (i,j) = triu_indices(128, k=1)[f-256]
// B=16384, F=8384. 549 MB fp32 output -> HBM-write-bound.
//
// R13 = R11 verbatim (champion, 96.7 us): R2 grid (33 f-windows x row
// groups, 1 feat/thread, LDS tile, lane-stride-1 conflict-free reads)
// + nt dword stores (R10, +2.8%) + BROWS=64 with decode/w-load hoisted
// above staging (R11, +2.2%). R12 (BROWS=128) regressed -> 64 is optimal.
// fp-exact: same op order as R2 (absmax 0.0 in R2-R12).

constexpr int BATCH = 16384;
constexpr int NIN   = 128;
constexpr int NFEAT = 2 * NIN + NIN * (NIN - 1) / 2;  // 8384
constexpr int TPB   = 256;
constexpr int BROWS = 64;

__device__ __forceinline__ int pair_off(int i) { return i * (NIN - 1) - (i * (i - 1)) / 2; }

__global__ __launch_bounds__(TPB) void cpl_kernel(const float* __restrict__ x,
                                                  const float* __restrict__ w,
                                                  float* __restrict__ out) {
    __shared__ float xs[BROWS * NIN];  // 32 KB

    const int tid = threadIdx.x;
    const int b0  = blockIdx.y * BROWS;
    const int f   = blockIdx.x * TPB + tid;
    const int fc  = min(f, NFEAT - 1);  // clamp for safe early decode/load

    // Issue w-load + decode FIRST: latency overlaps the staging loads below.
    const float wf = w[fc];
    int i1, i2, mode;  // 0=square, 1=single, 2=pair
    if (fc < NIN) {
        i1 = fc; i2 = fc; mode = 0;
    } else if (fc < 2 * NIN) {
        i1 = fc - NIN; i2 = fc - NIN; mode = 1;
    } else {
        const int p = fc - 2 * NIN;
        float s = sqrtf((float)(65025 - 8 * p));  // invert off(i) <= p
        int   i = (int)((255.0f - s) * 0.5f);
        i = min(max(i, 0), NIN - 2);
        while (pair_off(i + 1) <= p) ++i;  // exact integer fix-up
        while (pair_off(i)     >  p) --i;
        i1 = i;
        i2 = i + 1 + (p - pair_off(i));
        mode = 2;
    }

    // Cooperative tile load: 64 rows x 128 floats = 2048 float4, 8 per thread.
    {
        const float4* src = reinterpret_cast<const float4*>(x + (size_t)b0 * NIN);
        float4*       dst = reinterpret_cast<float4*>(xs);
#pragma unroll
        for (int k = 0; k < (BROWS * NIN / 4) / TPB; ++k)
            dst[k * TPB + tid] = src[k * TPB + tid];
    }
    __syncthreads();

    if (f >= NFEAT) return;

    float* op = out + (size_t)b0 * NFEAT + f;
#pragma unroll
    for (int b = 0; b < BROWS; ++b) {
        const float xi = xs[b * NIN + i1];
        const float xj = xs[b * NIN + i2];  // lane-stride-1: conflict-free
        float p = xi * xj;                  // squares & pairs
        if (mode == 1) p = xi;              // singles
        if (mode == 2) p *= 0.5f;           // pairs (same fp order as ref)
        __builtin_nontemporal_store(p * wf, op + (size_t)b * NFEAT);
    }
}

extern "C" void kernel_launch(void* const* d_in, const int* in_sizes, int n_in,
                              void* d_out, int out_size, void* d_ws, size_t ws_size,
                              hipStream_t stream) {
    const float* x = (const float*)d_in[0];  // [16384, 128]
    const float* w = (const float*)d_in[1];  // [8384]
    float*     out = (float*)d_out;          // [16384, 8384]

    dim3 grid((NFEAT + TPB - 1) / TPB,  // 33 feature windows
              BATCH / BROWS);           // 256 row groups
    cpl_kernel<<<grid, TPB, 0, stream>>>(x, w, out);
}